// Round 7
// baseline (339.706 us; speedup 1.0000x reference)
//
#include <hip/hip_runtime.h>
#include <hip/hip_bf16.h>
#include <stdint.h>

#define B_ 2
#define T_ 2048
#define C_ 1024
#define H_ 16
#define D_ 64

typedef __attribute__((ext_vector_type(8))) short short8;
typedef __attribute__((ext_vector_type(4))) float floatx4;

__device__ __forceinline__ float bf2f(uint16_t b) {
    return __uint_as_float(((uint32_t)b) << 16);
}
__device__ __forceinline__ uint16_t f2b(float f) {
    __hip_bfloat16 h = __float2bfloat16(f);  // RNE
    return *(uint16_t*)&h;
}

// ---- canonicalize x: fp32 -> bf16 -----------------------------------------
__global__ void canon_x(const float* __restrict__ in, uint16_t* __restrict__ out,
                        int n) {
    int i = (blockIdx.x * 256 + threadIdx.x) * 4;
    if (i >= n) return;
    float4 v = *(const float4*)(in + i);
    out[i + 0] = f2b(v.x);
    out[i + 1] = f2b(v.y);
    out[i + 2] = f2b(v.z);
    out[i + 3] = f2b(v.w);
}

// ---- transpose + convert: in [R,W] fp32 -> out [W,R] bf16 -----------------
__global__ void transpose_conv(const float* __restrict__ in, uint16_t* __restrict__ out,
                               int R, int W) {
    __shared__ uint16_t tile[32][33];
    int tx = threadIdx.x, ty = threadIdx.y;
    int c0 = blockIdx.x * 32, r0 = blockIdx.y * 32;
    #pragma unroll
    for (int i = 0; i < 32; i += 8)
        tile[ty + i][tx] = f2b(in[(size_t)(r0 + ty + i) * W + (c0 + tx)]);
    __syncthreads();
    #pragma unroll
    for (int i = 0; i < 32; i += 8)
        out[(size_t)(c0 + ty + i) * R + (r0 + tx)] = tile[tx][ty + i];
}

// ------- GEMM: C[M,N] = A[M,K] @ Bt[N,K]^T ; bf16 in, fp32 acc -------------
// 128x128 tile, 4 waves. Manual uint4 staging (measured faster than
// global_load_lds here: rest-time 61 vs 140 us — see R4/R6 post-mortems).
template <bool OUT_F32>
__global__ __launch_bounds__(256)
void gemm_bt(const uint16_t* __restrict__ A, const uint16_t* __restrict__ Bt,
             void* __restrict__ Cv, int M, int N, int K) {
    __shared__ uint16_t As[128][32];
    __shared__ uint16_t Bs[128][32];
    int tid = threadIdx.x;
    int wave = tid >> 6, lane = tid & 63;
    int quad = lane >> 4, l16 = lane & 15;
    int wr = (wave >> 1) * 64, wc = (wave & 1) * 64;
    int row0 = blockIdx.x * 128, col0 = blockIdx.y * 128;
    int srow = tid >> 1, scol = (tid & 1) * 16;

    floatx4 acc[4][4];
    #pragma unroll
    for (int i = 0; i < 4; i++)
        #pragma unroll
        for (int j = 0; j < 4; j++)
            acc[i][j] = (floatx4){0.f, 0.f, 0.f, 0.f};

    for (int k0 = 0; k0 < K; k0 += 32) {
        const uint4* ga = (const uint4*)(A + (size_t)(row0 + srow) * K + k0 + scol);
        const uint4* gb = (const uint4*)(Bt + (size_t)(col0 + srow) * K + k0 + scol);
        uint4 a0 = ga[0], a1 = ga[1];
        uint4 b0 = gb[0], b1 = gb[1];
        __syncthreads();
        *(uint4*)&As[srow][scol]     = a0;
        *(uint4*)&As[srow][scol + 8] = a1;
        *(uint4*)&Bs[srow][scol]     = b0;
        *(uint4*)&Bs[srow][scol + 8] = b1;
        __syncthreads();
        short8 af[4], bf[4];
        #pragma unroll
        for (int i = 0; i < 4; i++)
            af[i] = *(const short8*)&As[wr + i * 16 + l16][quad * 8];
        #pragma unroll
        for (int j = 0; j < 4; j++)
            bf[j] = *(const short8*)&Bs[wc + j * 16 + l16][quad * 8];
        #pragma unroll
        for (int i = 0; i < 4; i++)
            #pragma unroll
            for (int j = 0; j < 4; j++)
                acc[i][j] = __builtin_amdgcn_mfma_f32_16x16x32_bf16(
                    af[i], bf[j], acc[i][j], 0, 0, 0);
    }
    #pragma unroll
    for (int i = 0; i < 4; i++) {
        #pragma unroll
        for (int j = 0; j < 4; j++) {
            int rbase = row0 + wr + i * 16 + quad * 4;
            int cg = col0 + wc + j * 16 + l16;
            #pragma unroll
            for (int r = 0; r < 4; r++) {
                if (OUT_F32)
                    ((float*)Cv)[(size_t)(rbase + r) * N + cg] = acc[i][j][r];
                else
                    ((uint16_t*)Cv)[(size_t)(rbase + r) * N + cg] = f2b(acc[i][j][r]);
            }
        }
    }
}

// ---------------- MFMA flash attention with sink ---------------------------
// Block = 128 q rows (4 waves x 32 q) of one (b,h). Single-buffered K/V LDS
// (36.9 KB total -> 4 blocks/CU at launch_bounds(256,4)); register prefetch.
// Grid id: bh = id&31 (XCD pinning), g = id>>5, qb = g<8 ? 15-g : g-8 so each
// CU's two resident-block pairs sum to 34 staged ktiles (per-CU balance).
__global__ __launch_bounds__(256, 4)
void attn_mfma(const uint16_t* __restrict__ qkv,
               const float* __restrict__ sink,
               uint16_t* __restrict__ y) {
    __shared__ uint16_t Ks[64][72];     // [key][d]   9216 B
    __shared__ uint16_t Vt[64][72];     // [d][key]   9216 B (col-swizzled)
    __shared__ uint16_t Pl[4][32][72];  // per-wave [q][key] 18432 B

    int tid = threadIdx.x;
    int w = tid >> 6, lane = tid & 63;
    int quad = lane >> 4, l16 = lane & 15;

    int id = blockIdx.x;
    int bh = id & 31;
    int g = id >> 5;
    int qb = (g < 8) ? (15 - g) : (g - 8);
    int b = bh >> 4, h = bh & 15;
    int q0w = qb * 128 + w * 32;            // wave's first q row
    int ktiles = 2 * qb + 2;                // staged by the block
    int myktiles = 2 * qb + 1 + (w >> 1);   // computed by this wave

    const uint16_t* qkv_b = qkv + (size_t)b * T_ * 3072;

    // ---- Q fragments: 2 qt x 2 kd, pre-scaled by 1/8 (exact) ----
    short8 qf[2][2];
    #pragma unroll
    for (int qt = 0; qt < 2; qt++) {
        int qrow = q0w + qt * 16 + l16;
        #pragma unroll
        for (int kd = 0; kd < 2; kd++) {
            uint4 raw = *(const uint4*)(qkv_b + (size_t)qrow * 3072 + h * 64 +
                                        kd * 32 + quad * 8);
            const uint16_t* rp = (const uint16_t*)&raw;
            short8 f;
            #pragma unroll
            for (int j = 0; j < 8; j++)
                f[j] = (short)f2b(bf2f(rp[j]) * 0.125f);
            qf[qt][kd] = f;
        }
    }

    float m_s[2], l_s[2];
    m_s[0] = m_s[1] = sink[h];
    l_s[0] = l_s[1] = 1.0f;
    floatx4 acc_o[2][4];
    #pragma unroll
    for (int qt = 0; qt < 2; qt++)
        #pragma unroll
        for (int dt = 0; dt < 4; dt++)
            acc_o[qt][dt] = (floatx4){0.f, 0.f, 0.f, 0.f};

    // ---- staging map: thread (t2,dg): key rows 2t2,2t2+1, dims dg*8..+7 ----
    int t2 = tid >> 3;
    int dg = tid & 7;
    const uint16_t* kgp = qkv_b + 1024 + h * 64 + (size_t)(2 * t2) * 3072 + dg * 8;
    const uint16_t* vgp = kgp + 1024;
    int vcw = 2 * (t2 ^ (4 * dg));   // swizzled u16 col for V^T key-pair store

    // preload tile 0
    uint4 kr0 = *(const uint4*)(kgp);
    uint4 kr1 = *(const uint4*)(kgp + 3072);
    uint4 vr0 = *(const uint4*)(vgp);
    uint4 vr1 = *(const uint4*)(vgp + 3072);

    for (int kt = 0; kt < ktiles; kt++) {
        __syncthreads();   // all waves done reading previous tile
        // ---- store staged regs -> LDS ----
        *(uint4*)&Ks[2 * t2][dg * 8] = kr0;
        *(uint4*)&Ks[2 * t2 + 1][dg * 8] = kr1;
        {
            const uint16_t* a0 = (const uint16_t*)&vr0;
            const uint16_t* a1 = (const uint16_t*)&vr1;
            #pragma unroll
            for (int j = 0; j < 8; j++)
                *(uint32_t*)&Vt[dg * 8 + j][vcw] =
                    (uint32_t)a0[j] | ((uint32_t)a1[j] << 16);
        }
        __syncthreads();   // tile visible
        // ---- issue prefetch of tile kt+1 (in flight during compute) ----
        if (kt + 1 < ktiles) {
            size_t off = (size_t)(kt + 1) * 64 * 3072;
            kr0 = *(const uint4*)(kgp + off);
            kr1 = *(const uint4*)(kgp + off + 3072);
            vr0 = *(const uint4*)(vgp + off);
            vr1 = *(const uint4*)(vgp + off + 3072);
        }
        if (kt >= myktiles) continue;

        // ---- K and V fragments (shared by both qt) ----
        short8 kf[4][2];
        #pragma unroll
        for (int rt = 0; rt < 4; rt++) {
            kf[rt][0] = *(const short8*)&Ks[rt * 16 + l16][quad * 8];
            kf[rt][1] = *(const short8*)&Ks[rt * 16 + l16][32 + quad * 8];
        }
        short8 vf[2][4];
        #pragma unroll
        for (int kb = 0; kb < 2; kb++)
            #pragma unroll
            for (int dt = 0; dt < 4; dt++) {
                int d = dt * 16 + l16;
                int col = 2 * (((kb * 16) + quad * 4) ^ (4 * (d >> 3)));
                vf[kb][dt] = *(const short8*)&Vt[d][col];
            }
        #pragma unroll
        for (int qt = 0; qt < 2; qt++) {
            // ---- S^T = K * Q^T : key = rt*16+quad*4+r, q = l16 ----
            floatx4 acc_s[4];
            #pragma unroll
            for (int rt = 0; rt < 4; rt++)
                acc_s[rt] = (floatx4){0.f, 0.f, 0.f, 0.f};
            #pragma unroll
            for (int rt = 0; rt < 4; rt++) {
                acc_s[rt] = __builtin_amdgcn_mfma_f32_16x16x32_bf16(
                    kf[rt][0], qf[qt][0], acc_s[rt], 0, 0, 0);
                acc_s[rt] = __builtin_amdgcn_mfma_f32_16x16x32_bf16(
                    kf[rt][1], qf[qt][1], acc_s[rt], 0, 0, 0);
            }
            // ---- causal mask (this wave's diagonal tile only) ----
            if (kt * 64 + 63 > q0w) {
                int qg = q0w + qt * 16 + l16;
                #pragma unroll
                for (int rt = 0; rt < 4; rt++) {
                    int kg = kt * 64 + rt * 16 + quad * 4;
                    #pragma unroll
                    for (int r = 0; r < 4; r++)
                        if (kg + r > qg) acc_s[rt][r] = -1e30f;
                }
            }
            // ---- online softmax (q = l16; reduce across quads) ----
            float mx = -1e30f;
            #pragma unroll
            for (int rt = 0; rt < 4; rt++)
                #pragma unroll
                for (int r = 0; r < 4; r++) mx = fmaxf(mx, acc_s[rt][r]);
            mx = fmaxf(mx, __shfl_xor(mx, 16));
            mx = fmaxf(mx, __shfl_xor(mx, 32));
            float mnew = fmaxf(m_s[qt], mx);
            float alpha = __expf(m_s[qt] - mnew);
            m_s[qt] = mnew;
            float psum = 0.f;
            #pragma unroll
            for (int rt = 0; rt < 4; rt++) {
                float p0 = __expf(acc_s[rt][0] - mnew);
                float p1 = __expf(acc_s[rt][1] - mnew);
                float p2 = __expf(acc_s[rt][2] - mnew);
                float p3 = __expf(acc_s[rt][3] - mnew);
                psum += (p0 + p1) + (p2 + p3);
                uint2 pk;
                pk.x = (uint32_t)f2b(p0) | ((uint32_t)f2b(p1) << 16);
                pk.y = (uint32_t)f2b(p2) | ((uint32_t)f2b(p3) << 16);
                *(uint2*)&Pl[w][qt * 16 + l16][rt * 16 + quad * 4] = pk;
            }
            psum += __shfl_xor(psum, 16);
            psum += __shfl_xor(psum, 32);
            l_s[qt] = l_s[qt] * alpha + psum;
            #pragma unroll
            for (int r = 0; r < 4; r++) {
                float ar = __shfl(alpha, (lane & 48) | (quad * 4 + r));
                #pragma unroll
                for (int dt = 0; dt < 4; dt++) acc_o[qt][dt][r] *= ar;
            }
            // ---- O += P * V ----
            #pragma unroll
            for (int kb = 0; kb < 2; kb++) {
                short8 pf = *(const short8*)&Pl[w][qt * 16 + l16][kb * 32 + quad * 8];
                #pragma unroll
                for (int dt = 0; dt < 4; dt++)
                    acc_o[qt][dt] = __builtin_amdgcn_mfma_f32_16x16x32_bf16(
                        pf, vf[kb][dt], acc_o[qt][dt], 0, 0, 0);
            }
        }
    }

    // ---- epilogue: normalize by l (per-q via in-quad shuffle), store bf16 --
    #pragma unroll
    for (int qt = 0; qt < 2; qt++) {
        #pragma unroll
        for (int r = 0; r < 4; r++) {
            float lr = __shfl(l_s[qt], (lane & 48) | (quad * 4 + r));
            float inv = 1.0f / lr;
            int qg = q0w + qt * 16 + quad * 4 + r;
            uint16_t* yp = y + (size_t)(b * T_ + qg) * 1024 + h * 64;
            #pragma unroll
            for (int dt = 0; dt < 4; dt++)
                yp[dt * 16 + l16] = f2b(acc_o[qt][dt][r] * inv);
        }
    }
}

extern "C" void kernel_launch(void* const* d_in, const int* in_sizes, int n_in,
                              void* d_out, int out_size, void* d_ws, size_t ws_size,
                              hipStream_t stream) {
    const float* x      = (const float*)d_in[0];  // [B,T,C] fp32
    const float* w_qkv  = (const float*)d_in[1];  // [C, 3HD] fp32
    const float* w_proj = (const float*)d_in[2];  // [HD, C] fp32
    const float* sink   = (const float*)d_in[3];  // [H] fp32
    float* out          = (float*)d_out;          // [B,T,C] fp32

    char* ws = (char*)d_ws;
    uint16_t* wt_qkv  = (uint16_t*)ws;                       // [3072,1024] 6.29 MB
    uint16_t* wt_proj = (uint16_t*)(ws + 6291456);           // [1024,1024] 2.10 MB
    uint16_t* x_c     = (uint16_t*)(ws + 8388608);           // [4096,1024] 8.39 MB
    uint16_t* qkv     = (uint16_t*)(ws + 16777216);          // [4096,3072] 25.17 MB
    uint16_t* yb      = (uint16_t*)(ws + 41943040);          // [4096,1024] 8.39 MB

    canon_x<<<4194304 / 1024, 256, 0, stream>>>(x, x_c, 4194304);
    transpose_conv<<<dim3(3072 / 32, 1024 / 32), dim3(32, 8), 0, stream>>>(
        w_qkv, wt_qkv, 1024, 3072);
    transpose_conv<<<dim3(1024 / 32, 1024 / 32), dim3(32, 8), 0, stream>>>(
        w_proj, wt_proj, 1024, 1024);

    gemm_bt<false><<<dim3(4096 / 128, 3072 / 128), 256, 0, stream>>>(
        x_c, wt_qkv, qkv, 4096, 3072, 1024);

    // 512 blocks: bh = id&31 (XCD pinning), per-CU big/small qb pairing
    attn_mfma<<<dim3(16 * 32), 256, 0, stream>>>(qkv, sink, yb);

    gemm_bt<true><<<dim3(4096 / 128, 1024 / 128), 256, 0, stream>>>(
        yb, wt_proj, out, 4096, 1024, 1024);
}

// Round 8
// 269.708 us; speedup vs baseline: 1.2595x; 1.2595x over previous
//
#include <hip/hip_runtime.h>
#include <hip/hip_bf16.h>
#include <stdint.h>

#define B_ 2
#define T_ 2048
#define C_ 1024
#define H_ 16
#define D_ 64

typedef __attribute__((ext_vector_type(8))) short short8;
typedef __attribute__((ext_vector_type(4))) float floatx4;

__device__ __forceinline__ float bf2f(uint16_t b) {
    return __uint_as_float(((uint32_t)b) << 16);
}
__device__ __forceinline__ uint16_t f2b(float f) {
    __hip_bfloat16 h = __float2bfloat16(f);  // RNE
    return *(uint16_t*)&h;
}

// ---- canonicalize x: fp32 -> bf16 -----------------------------------------
__global__ void canon_x(const float* __restrict__ in, uint16_t* __restrict__ out,
                        int n) {
    int i = (blockIdx.x * 256 + threadIdx.x) * 4;
    if (i >= n) return;
    float4 v = *(const float4*)(in + i);
    out[i + 0] = f2b(v.x);
    out[i + 1] = f2b(v.y);
    out[i + 2] = f2b(v.z);
    out[i + 3] = f2b(v.w);
}

// ---- transpose + convert: in [R,W] fp32 -> out [W,R] bf16 -----------------
__global__ void transpose_conv(const float* __restrict__ in, uint16_t* __restrict__ out,
                               int R, int W) {
    __shared__ uint16_t tile[32][33];
    int tx = threadIdx.x, ty = threadIdx.y;
    int c0 = blockIdx.x * 32, r0 = blockIdx.y * 32;
    #pragma unroll
    for (int i = 0; i < 32; i += 8)
        tile[ty + i][tx] = f2b(in[(size_t)(r0 + ty + i) * W + (c0 + tx)]);
    __syncthreads();
    #pragma unroll
    for (int i = 0; i < 32; i += 8)
        out[(size_t)(c0 + ty + i) * R + (r0 + tx)] = tile[tx][ty + i];
}

// ------- GEMM: C[M,N] = A[M,K] @ Bt[N,K]^T ; bf16 in, fp32 acc -------------
// 128x128 tile, 4 waves, manual uint4 staging.
template <bool OUT_F32>
__global__ __launch_bounds__(256)
void gemm_bt(const uint16_t* __restrict__ A, const uint16_t* __restrict__ Bt,
             void* __restrict__ Cv, int M, int N, int K) {
    __shared__ uint16_t As[128][32];
    __shared__ uint16_t Bs[128][32];
    int tid = threadIdx.x;
    int wave = tid >> 6, lane = tid & 63;
    int quad = lane >> 4, l16 = lane & 15;
    int wr = (wave >> 1) * 64, wc = (wave & 1) * 64;
    int row0 = blockIdx.x * 128, col0 = blockIdx.y * 128;
    int srow = tid >> 1, scol = (tid & 1) * 16;

    floatx4 acc[4][4];
    #pragma unroll
    for (int i = 0; i < 4; i++)
        #pragma unroll
        for (int j = 0; j < 4; j++)
            acc[i][j] = (floatx4){0.f, 0.f, 0.f, 0.f};

    for (int k0 = 0; k0 < K; k0 += 32) {
        const uint4* ga = (const uint4*)(A + (size_t)(row0 + srow) * K + k0 + scol);
        const uint4* gb = (const uint4*)(Bt + (size_t)(col0 + srow) * K + k0 + scol);
        uint4 a0 = ga[0], a1 = ga[1];
        uint4 b0 = gb[0], b1 = gb[1];
        __syncthreads();
        *(uint4*)&As[srow][scol]     = a0;
        *(uint4*)&As[srow][scol + 8] = a1;
        *(uint4*)&Bs[srow][scol]     = b0;
        *(uint4*)&Bs[srow][scol + 8] = b1;
        __syncthreads();
        short8 af[4], bf[4];
        #pragma unroll
        for (int i = 0; i < 4; i++)
            af[i] = *(const short8*)&As[wr + i * 16 + l16][quad * 8];
        #pragma unroll
        for (int j = 0; j < 4; j++)
            bf[j] = *(const short8*)&Bs[wc + j * 16 + l16][quad * 8];
        #pragma unroll
        for (int i = 0; i < 4; i++)
            #pragma unroll
            for (int j = 0; j < 4; j++)
                acc[i][j] = __builtin_amdgcn_mfma_f32_16x16x32_bf16(
                    af[i], bf[j], acc[i][j], 0, 0, 0);
    }
    #pragma unroll
    for (int i = 0; i < 4; i++) {
        #pragma unroll
        for (int j = 0; j < 4; j++) {
            int rbase = row0 + wr + i * 16 + quad * 4;
            int cg = col0 + wc + j * 16 + l16;
            #pragma unroll
            for (int r = 0; r < 4; r++) {
                if (OUT_F32)
                    ((float*)Cv)[(size_t)(rbase + r) * N + cg] = acc[i][j][r];
                else
                    ((uint16_t*)Cv)[(size_t)(rbase + r) * N + cg] = f2b(acc[i][j][r]);
            }
        }
    }
}

// ---------------- MFMA flash attention with sink ---------------------------
// Block = 128 q rows (4 waves x 32 q) of one (b,h). Single-buffered K/V LDS
// (36.9 KB). launch_bounds(256,3): unified VGPR+AGPR cap 170 >= ~156 demand
// -> NO SPILL (R7's (256,4)=128 cap spilled: WRITE_SIZE 294 MB). 3 blocks/CU.
// Grid id: bh = id&31 (XCD pinning), g = id>>5, qb = g<8 ? 15-g : g-8 for
// per-CU big/small pairing (constant 34 staged ktiles per CU).
__global__ __launch_bounds__(256, 3)
void attn_mfma(const uint16_t* __restrict__ qkv,
               const float* __restrict__ sink,
               uint16_t* __restrict__ y) {
    __shared__ uint16_t Ks[64][72];     // [key][d]   9216 B
    __shared__ uint16_t Vt[64][72];     // [d][key]   9216 B (col-swizzled)
    __shared__ uint16_t Pl[4][32][72];  // per-wave [q][key] 18432 B

    int tid = threadIdx.x;
    int w = tid >> 6, lane = tid & 63;
    int quad = lane >> 4, l16 = lane & 15;

    int id = blockIdx.x;
    int bh = id & 31;
    int g = id >> 5;
    int qb = (g < 8) ? (15 - g) : (g - 8);
    int b = bh >> 4, h = bh & 15;
    int q0w = qb * 128 + w * 32;            // wave's first q row
    int ktiles = 2 * qb + 2;                // staged by the block
    int myktiles = 2 * qb + 1 + (w >> 1);   // computed by this wave

    const uint16_t* qkv_b = qkv + (size_t)b * T_ * 3072;

    // ---- Q fragments: 2 qt x 2 kd, pre-scaled by 1/8 (exact) ----
    short8 qf[2][2];
    #pragma unroll
    for (int qt = 0; qt < 2; qt++) {
        int qrow = q0w + qt * 16 + l16;
        #pragma unroll
        for (int kd = 0; kd < 2; kd++) {
            uint4 raw = *(const uint4*)(qkv_b + (size_t)qrow * 3072 + h * 64 +
                                        kd * 32 + quad * 8);
            const uint16_t* rp = (const uint16_t*)&raw;
            short8 f;
            #pragma unroll
            for (int j = 0; j < 8; j++)
                f[j] = (short)f2b(bf2f(rp[j]) * 0.125f);
            qf[qt][kd] = f;
        }
    }

    float m_s[2], l_s[2];
    m_s[0] = m_s[1] = sink[h];
    l_s[0] = l_s[1] = 1.0f;
    floatx4 acc_o[2][4];
    #pragma unroll
    for (int qt = 0; qt < 2; qt++)
        #pragma unroll
        for (int dt = 0; dt < 4; dt++)
            acc_o[qt][dt] = (floatx4){0.f, 0.f, 0.f, 0.f};

    // ---- staging map: thread (t2,dg): key rows 2t2,2t2+1, dims dg*8..+7 ----
    int t2 = tid >> 3;
    int dg = tid & 7;
    const uint16_t* kgp = qkv_b + 1024 + h * 64 + (size_t)(2 * t2) * 3072 + dg * 8;
    const uint16_t* vgp = kgp + 1024;
    int vcw = 2 * (t2 ^ (4 * dg));   // swizzled u16 col for V^T key-pair store

    // preload tile 0
    uint4 kr0 = *(const uint4*)(kgp);
    uint4 kr1 = *(const uint4*)(kgp + 3072);
    uint4 vr0 = *(const uint4*)(vgp);
    uint4 vr1 = *(const uint4*)(vgp + 3072);

    for (int kt = 0; kt < ktiles; kt++) {
        __syncthreads();   // all waves done reading previous tile
        // ---- store staged regs -> LDS ----
        *(uint4*)&Ks[2 * t2][dg * 8] = kr0;
        *(uint4*)&Ks[2 * t2 + 1][dg * 8] = kr1;
        {
            const uint16_t* a0 = (const uint16_t*)&vr0;
            const uint16_t* a1 = (const uint16_t*)&vr1;
            #pragma unroll
            for (int j = 0; j < 8; j++)
                *(uint32_t*)&Vt[dg * 8 + j][vcw] =
                    (uint32_t)a0[j] | ((uint32_t)a1[j] << 16);
        }
        __syncthreads();   // tile visible
        // ---- issue prefetch of tile kt+1 (in flight during compute) ----
        if (kt + 1 < ktiles) {
            size_t off = (size_t)(kt + 1) * 64 * 3072;
            kr0 = *(const uint4*)(kgp + off);
            kr1 = *(const uint4*)(kgp + off + 3072);
            vr0 = *(const uint4*)(vgp + off);
            vr1 = *(const uint4*)(vgp + off + 3072);
        }
        if (kt >= myktiles) continue;

        // ---- K and V fragments (shared by both qt) ----
        short8 kf[4][2];
        #pragma unroll
        for (int rt = 0; rt < 4; rt++) {
            kf[rt][0] = *(const short8*)&Ks[rt * 16 + l16][quad * 8];
            kf[rt][1] = *(const short8*)&Ks[rt * 16 + l16][32 + quad * 8];
        }
        short8 vf[2][4];
        #pragma unroll
        for (int kb = 0; kb < 2; kb++)
            #pragma unroll
            for (int dt = 0; dt < 4; dt++) {
                int d = dt * 16 + l16;
                int col = 2 * (((kb * 16) + quad * 4) ^ (4 * (d >> 3)));
                vf[kb][dt] = *(const short8*)&Vt[d][col];
            }
        #pragma unroll
        for (int qt = 0; qt < 2; qt++) {
            // ---- S^T = K * Q^T : key = rt*16+quad*4+r, q = l16 ----
            floatx4 acc_s[4];
            #pragma unroll
            for (int rt = 0; rt < 4; rt++)
                acc_s[rt] = (floatx4){0.f, 0.f, 0.f, 0.f};
            #pragma unroll
            for (int rt = 0; rt < 4; rt++) {
                acc_s[rt] = __builtin_amdgcn_mfma_f32_16x16x32_bf16(
                    kf[rt][0], qf[qt][0], acc_s[rt], 0, 0, 0);
                acc_s[rt] = __builtin_amdgcn_mfma_f32_16x16x32_bf16(
                    kf[rt][1], qf[qt][1], acc_s[rt], 0, 0, 0);
            }
            // ---- causal mask (this wave's diagonal tile only) ----
            if (kt * 64 + 63 > q0w) {
                int qg = q0w + qt * 16 + l16;
                #pragma unroll
                for (int rt = 0; rt < 4; rt++) {
                    int kg = kt * 64 + rt * 16 + quad * 4;
                    #pragma unroll
                    for (int r = 0; r < 4; r++)
                        if (kg + r > qg) acc_s[rt][r] = -1e30f;
                }
            }
            // ---- online softmax (q = l16; reduce across quads) ----
            float mx = -1e30f;
            #pragma unroll
            for (int rt = 0; rt < 4; rt++)
                #pragma unroll
                for (int r = 0; r < 4; r++) mx = fmaxf(mx, acc_s[rt][r]);
            mx = fmaxf(mx, __shfl_xor(mx, 16));
            mx = fmaxf(mx, __shfl_xor(mx, 32));
            float mnew = fmaxf(m_s[qt], mx);
            float alpha = __expf(m_s[qt] - mnew);
            m_s[qt] = mnew;
            float psum = 0.f;
            #pragma unroll
            for (int rt = 0; rt < 4; rt++) {
                float p0 = __expf(acc_s[rt][0] - mnew);
                float p1 = __expf(acc_s[rt][1] - mnew);
                float p2 = __expf(acc_s[rt][2] - mnew);
                float p3 = __expf(acc_s[rt][3] - mnew);
                psum += (p0 + p1) + (p2 + p3);
                uint2 pk;
                pk.x = (uint32_t)f2b(p0) | ((uint32_t)f2b(p1) << 16);
                pk.y = (uint32_t)f2b(p2) | ((uint32_t)f2b(p3) << 16);
                *(uint2*)&Pl[w][qt * 16 + l16][rt * 16 + quad * 4] = pk;
            }
            psum += __shfl_xor(psum, 16);
            psum += __shfl_xor(psum, 32);
            l_s[qt] = l_s[qt] * alpha + psum;
            #pragma unroll
            for (int r = 0; r < 4; r++) {
                float ar = __shfl(alpha, (lane & 48) | (quad * 4 + r));
                #pragma unroll
                for (int dt = 0; dt < 4; dt++) acc_o[qt][dt][r] *= ar;
            }
            // ---- O += P * V ----
            #pragma unroll
            for (int kb = 0; kb < 2; kb++) {
                short8 pf = *(const short8*)&Pl[w][qt * 16 + l16][kb * 32 + quad * 8];
                #pragma unroll
                for (int dt = 0; dt < 4; dt++)
                    acc_o[qt][dt] = __builtin_amdgcn_mfma_f32_16x16x32_bf16(
                        pf, vf[kb][dt], acc_o[qt][dt], 0, 0, 0);
            }
        }
    }

    // ---- epilogue: normalize by l (per-q via in-quad shuffle), store bf16 --
    #pragma unroll
    for (int qt = 0; qt < 2; qt++) {
        #pragma unroll
        for (int r = 0; r < 4; r++) {
            float lr = __shfl(l_s[qt], (lane & 48) | (quad * 4 + r));
            float inv = 1.0f / lr;
            int qg = q0w + qt * 16 + quad * 4 + r;
            uint16_t* yp = y + (size_t)(b * T_ + qg) * 1024 + h * 64;
            #pragma unroll
            for (int dt = 0; dt < 4; dt++)
                yp[dt * 16 + l16] = f2b(acc_o[qt][dt][r] * inv);
        }
    }
}

extern "C" void kernel_launch(void* const* d_in, const int* in_sizes, int n_in,
                              void* d_out, int out_size, void* d_ws, size_t ws_size,
                              hipStream_t stream) {
    const float* x      = (const float*)d_in[0];  // [B,T,C] fp32
    const float* w_qkv  = (const float*)d_in[1];  // [C, 3HD] fp32
    const float* w_proj = (const float*)d_in[2];  // [HD, C] fp32
    const float* sink   = (const float*)d_in[3];  // [H] fp32
    float* out          = (float*)d_out;          // [B,T,C] fp32

    char* ws = (char*)d_ws;
    uint16_t* wt_qkv  = (uint16_t*)ws;                       // [3072,1024] 6.29 MB
    uint16_t* wt_proj = (uint16_t*)(ws + 6291456);           // [1024,1024] 2.10 MB
    uint16_t* x_c     = (uint16_t*)(ws + 8388608);           // [4096,1024] 8.39 MB
    uint16_t* qkv     = (uint16_t*)(ws + 16777216);          // [4096,3072] 25.17 MB
    uint16_t* yb      = (uint16_t*)(ws + 41943040);          // [4096,1024] 8.39 MB

    canon_x<<<4194304 / 1024, 256, 0, stream>>>(x, x_c, 4194304);
    transpose_conv<<<dim3(3072 / 32, 1024 / 32), dim3(32, 8), 0, stream>>>(
        w_qkv, wt_qkv, 1024, 3072);
    transpose_conv<<<dim3(1024 / 32, 1024 / 32), dim3(32, 8), 0, stream>>>(
        w_proj, wt_proj, 1024, 1024);

    gemm_bt<false><<<dim3(4096 / 128, 3072 / 128), 256, 0, stream>>>(
        x_c, wt_qkv, qkv, 4096, 3072, 1024);

    // 512 blocks: bh = id&31 (XCD pinning), per-CU big/small qb pairing
    attn_mfma<<<dim3(16 * 32), 256, 0, stream>>>(qkv, sink, yb);

    gemm_bt<true><<<dim3(4096 / 128, 1024 / 128), 256, 0, stream>>>(
        yb, wt_proj, out, 4096, 1024, 1024);
}

// Round 9
// 204.715 us; speedup vs baseline: 1.6594x; 1.3175x over previous
//
#include <hip/hip_runtime.h>
#include <hip/hip_bf16.h>
#include <stdint.h>

#define B_ 2
#define T_ 2048
#define C_ 1024
#define H_ 16
#define D_ 64

typedef __attribute__((ext_vector_type(8))) short short8;
typedef __attribute__((ext_vector_type(4))) float floatx4;

__device__ __forceinline__ float bf2f(uint16_t b) {
    return __uint_as_float(((uint32_t)b) << 16);
}
__device__ __forceinline__ uint16_t f2b(float f) {
    __hip_bfloat16 h = __float2bfloat16(f);  // RNE
    return *(uint16_t*)&h;
}

// ---- canonicalize x: fp32 -> bf16 -----------------------------------------
__global__ void canon_x(const float* __restrict__ in, uint16_t* __restrict__ out,
                        int n) {
    int i = (blockIdx.x * 256 + threadIdx.x) * 4;
    if (i >= n) return;
    float4 v = *(const float4*)(in + i);
    out[i + 0] = f2b(v.x);
    out[i + 1] = f2b(v.y);
    out[i + 2] = f2b(v.z);
    out[i + 3] = f2b(v.w);
}

// ---- transpose + convert: in [R,W] fp32 -> out [W,R] bf16 -----------------
__global__ void transpose_conv(const float* __restrict__ in, uint16_t* __restrict__ out,
                               int R, int W) {
    __shared__ uint16_t tile[32][33];
    int tx = threadIdx.x, ty = threadIdx.y;
    int c0 = blockIdx.x * 32, r0 = blockIdx.y * 32;
    #pragma unroll
    for (int i = 0; i < 32; i += 8)
        tile[ty + i][tx] = f2b(in[(size_t)(r0 + ty + i) * W + (c0 + tx)]);
    __syncthreads();
    #pragma unroll
    for (int i = 0; i < 32; i += 8)
        out[(size_t)(c0 + ty + i) * R + (r0 + tx)] = tile[tx][ty + i];
}

// ------- GEMM: C[M,N] = A[M,K] @ Bt[N,K]^T ; bf16 in, fp32 acc -------------
// 128x128 tile, 4 waves, manual uint4 staging.
template <bool OUT_F32>
__global__ __launch_bounds__(256)
void gemm_bt(const uint16_t* __restrict__ A, const uint16_t* __restrict__ Bt,
             void* __restrict__ Cv, int M, int N, int K) {
    __shared__ uint16_t As[128][32];
    __shared__ uint16_t Bs[128][32];
    int tid = threadIdx.x;
    int wave = tid >> 6, lane = tid & 63;
    int quad = lane >> 4, l16 = lane & 15;
    int wr = (wave >> 1) * 64, wc = (wave & 1) * 64;
    int row0 = blockIdx.x * 128, col0 = blockIdx.y * 128;
    int srow = tid >> 1, scol = (tid & 1) * 16;

    floatx4 acc[4][4];
    #pragma unroll
    for (int i = 0; i < 4; i++)
        #pragma unroll
        for (int j = 0; j < 4; j++)
            acc[i][j] = (floatx4){0.f, 0.f, 0.f, 0.f};

    for (int k0 = 0; k0 < K; k0 += 32) {
        const uint4* ga = (const uint4*)(A + (size_t)(row0 + srow) * K + k0 + scol);
        const uint4* gb = (const uint4*)(Bt + (size_t)(col0 + srow) * K + k0 + scol);
        uint4 a0 = ga[0], a1 = ga[1];
        uint4 b0 = gb[0], b1 = gb[1];
        __syncthreads();
        *(uint4*)&As[srow][scol]     = a0;
        *(uint4*)&As[srow][scol + 8] = a1;
        *(uint4*)&Bs[srow][scol]     = b0;
        *(uint4*)&Bs[srow][scol + 8] = b1;
        __syncthreads();
        short8 af[4], bf[4];
        #pragma unroll
        for (int i = 0; i < 4; i++)
            af[i] = *(const short8*)&As[wr + i * 16 + l16][quad * 8];
        #pragma unroll
        for (int j = 0; j < 4; j++)
            bf[j] = *(const short8*)&Bs[wc + j * 16 + l16][quad * 8];
        #pragma unroll
        for (int i = 0; i < 4; i++)
            #pragma unroll
            for (int j = 0; j < 4; j++)
                acc[i][j] = __builtin_amdgcn_mfma_f32_16x16x32_bf16(
                    af[i], bf[j], acc[i][j], 0, 0, 0);
    }
    #pragma unroll
    for (int i = 0; i < 4; i++) {
        #pragma unroll
        for (int j = 0; j < 4; j++) {
            int rbase = row0 + wr + i * 16 + quad * 4;
            int cg = col0 + wc + j * 16 + l16;
            #pragma unroll
            for (int r = 0; r < 4; r++) {
                if (OUT_F32)
                    ((float*)Cv)[(size_t)(rbase + r) * N + cg] = acc[i][j][r];
                else
                    ((uint16_t*)Cv)[(size_t)(rbase + r) * N + cg] = f2b(acc[i][j][r]);
            }
        }
    }
}

// ---- repack K,V into MFMA-fragment-linear layout --------------------------
// Per (bh, ktile of 64 keys): 8 chunks x 64 lanes x 8 bf16 (=8 KB each of K,V)
// K chunk c=rt*2+kd, lane=quad*16+l16 -> elem (key=rt*16+l16, d=kd*32+quad*8+j)
// V chunk c=kb*4+dt, lane            -> elem (key=kb*32+quad*8+j, d=dt*16+l16)
// so attention waves load fragments with perfectly coalesced b128 reads.
__global__ __launch_bounds__(256)
void repack_kv(const uint16_t* __restrict__ qkv,
               uint16_t* __restrict__ Kf, uint16_t* __restrict__ Vf) {
    __shared__ uint16_t Ks[64][80];
    __shared__ uint16_t Vs[64][80];
    int tid = threadIdx.x;
    int kt = blockIdx.x & 31;
    int bh = blockIdx.x >> 5;
    int b = bh >> 4, h = bh & 15;
    int t2 = tid >> 3, dg = tid & 7;
    const uint16_t* base = qkv + (size_t)(b * T_ + kt * 64 + 2 * t2) * 3072 +
                           1024 + h * 64 + dg * 8;
    uint4 k0 = *(const uint4*)(base);
    uint4 k1 = *(const uint4*)(base + 3072);
    uint4 v0 = *(const uint4*)(base + 1024);
    uint4 v1 = *(const uint4*)(base + 1024 + 3072);
    *(uint4*)&Ks[2 * t2][dg * 8] = k0;
    *(uint4*)&Ks[2 * t2 + 1][dg * 8] = k1;
    *(uint4*)&Vs[2 * t2][dg * 8] = v0;
    *(uint4*)&Vs[2 * t2 + 1][dg * 8] = v1;
    __syncthreads();
    size_t obase = ((size_t)bh * 32 + kt) * 4096;
    #pragma unroll
    for (int t = 0; t < 2; t++) {
        int it = tid + t * 256;
        int c = it >> 6, lane = it & 63;
        int quad = lane >> 4, l16 = lane & 15;
        int rt = c >> 1, kd = c & 1;
        uint4 kk = *(const uint4*)&Ks[rt * 16 + l16][kd * 32 + quad * 8];
        *(uint4*)(Kf + obase + (size_t)(c * 64 + lane) * 8) = kk;
        int kb = c >> 2, dt = c & 3;
        uint16_t tmp[8];
        #pragma unroll
        for (int j = 0; j < 8; j++)
            tmp[j] = Vs[kb * 32 + quad * 8 + j][dt * 16 + l16];
        *(uint4*)(Vf + obase + (size_t)(c * 64 + lane) * 8) = *(uint4*)tmp;
    }
}

// ---------------- barrier-free MFMA flash attention with sink --------------
// 4 independent waves/block; wave = (bh = (bid&7)+8w, strip of 32 q).
// K/V fragments loaded straight from fragment-linear global (L2, XCD-pinned,
// coalesced b128) -> NO K/V LDS, NO __syncthreads in the K-loop. Only the
// wave-private P round-trip uses LDS. kf pipelined one tile ahead.
// Strip map: i=bid>>3, strip = i<32 ? 63-i : i-32  (per-CU big/small pairing).
__global__ __launch_bounds__(256, 2)
void attn_mfma(const uint16_t* __restrict__ qkv,
               const uint16_t* __restrict__ Kf, const uint16_t* __restrict__ Vf,
               const float* __restrict__ sink, uint16_t* __restrict__ y) {
    __shared__ uint16_t Pl[4][32][72];  // per-wave [q][key] 18432 B

    int tid = threadIdx.x;
    int w = tid >> 6, lane = tid & 63;
    int quad = lane >> 4, l16 = lane & 15;

    int bid = blockIdx.x;
    int bh = (bid & 7) + 8 * w;            // wave's (b,h); same-XCD per head
    int i = bid >> 3;
    int strip = (i < 32) ? (63 - i) : (i - 32);
    int b = bh >> 4, h = bh & 15;
    int q0w = strip * 32;                  // wave's first q row
    int nkt = (strip >> 1) + 1;            // 64-key tiles this wave needs

    const uint16_t* qkv_b = qkv + (size_t)b * T_ * 3072;
    const uint16_t* kfb = Kf + (size_t)bh * 32 * 4096;
    const uint16_t* vfb = Vf + (size_t)bh * 32 * 4096;

    // ---- Q fragments: 2 qt x 2 kd, pre-scaled by 1/8 (exact) ----
    short8 qf[2][2];
    #pragma unroll
    for (int qt = 0; qt < 2; qt++) {
        int qrow = q0w + qt * 16 + l16;
        #pragma unroll
        for (int kd = 0; kd < 2; kd++) {
            uint4 raw = *(const uint4*)(qkv_b + (size_t)qrow * 3072 + h * 64 +
                                        kd * 32 + quad * 8);
            const uint16_t* rp = (const uint16_t*)&raw;
            short8 f;
            #pragma unroll
            for (int j = 0; j < 8; j++)
                f[j] = (short)f2b(bf2f(rp[j]) * 0.125f);
            qf[qt][kd] = f;
        }
    }

    float m_s[2], l_s[2];
    m_s[0] = m_s[1] = sink[h];
    l_s[0] = l_s[1] = 1.0f;
    floatx4 acc_o[2][4];
    #pragma unroll
    for (int qt = 0; qt < 2; qt++)
        #pragma unroll
        for (int dt = 0; dt < 4; dt++)
            acc_o[qt][dt] = (floatx4){0.f, 0.f, 0.f, 0.f};

    // ---- preload kf for tile 0 ----
    short8 kfc[4][2];
    #pragma unroll
    for (int rt = 0; rt < 4; rt++)
        #pragma unroll
        for (int kd = 0; kd < 2; kd++)
            kfc[rt][kd] = *(const short8*)(kfb + (size_t)((rt * 2 + kd) * 64 + lane) * 8);

    for (int kt = 0; kt < nkt; kt++) {
        // ---- V fragments for this tile (used late -> latency hidden) ----
        const uint16_t* vp = vfb + (size_t)kt * 4096;
        short8 vf[2][4];
        #pragma unroll
        for (int kb = 0; kb < 2; kb++)
            #pragma unroll
            for (int dt = 0; dt < 4; dt++)
                vf[kb][dt] = *(const short8*)(vp + (size_t)((kb * 4 + dt) * 64 + lane) * 8);
        // ---- prefetch next tile's kf ----
        short8 kfn[4][2];
        if (kt + 1 < nkt) {
            const uint16_t* kp = kfb + (size_t)(kt + 1) * 4096;
            #pragma unroll
            for (int rt = 0; rt < 4; rt++)
                #pragma unroll
                for (int kd = 0; kd < 2; kd++)
                    kfn[rt][kd] = *(const short8*)(kp + (size_t)((rt * 2 + kd) * 64 + lane) * 8);
        }
        bool maskit = (kt == nkt - 1);
        #pragma unroll
        for (int qt = 0; qt < 2; qt++) {
            // ---- S^T = K * Q^T : key = rt*16+quad*4+r, q = l16 ----
            floatx4 acc_s[4];
            #pragma unroll
            for (int rt = 0; rt < 4; rt++)
                acc_s[rt] = (floatx4){0.f, 0.f, 0.f, 0.f};
            #pragma unroll
            for (int rt = 0; rt < 4; rt++) {
                acc_s[rt] = __builtin_amdgcn_mfma_f32_16x16x32_bf16(
                    kfc[rt][0], qf[qt][0], acc_s[rt], 0, 0, 0);
                acc_s[rt] = __builtin_amdgcn_mfma_f32_16x16x32_bf16(
                    kfc[rt][1], qf[qt][1], acc_s[rt], 0, 0, 0);
            }
            // ---- causal mask (last tile only) ----
            if (maskit) {
                int qg = q0w + qt * 16 + l16;
                #pragma unroll
                for (int rt = 0; rt < 4; rt++) {
                    int kg = kt * 64 + rt * 16 + quad * 4;
                    #pragma unroll
                    for (int r = 0; r < 4; r++)
                        if (kg + r > qg) acc_s[rt][r] = -1e30f;
                }
            }
            // ---- online softmax (q = l16; reduce across quads) ----
            float mx = -1e30f;
            #pragma unroll
            for (int rt = 0; rt < 4; rt++)
                #pragma unroll
                for (int r = 0; r < 4; r++) mx = fmaxf(mx, acc_s[rt][r]);
            mx = fmaxf(mx, __shfl_xor(mx, 16));
            mx = fmaxf(mx, __shfl_xor(mx, 32));
            float mnew = fmaxf(m_s[qt], mx);
            float alpha = __expf(m_s[qt] - mnew);
            m_s[qt] = mnew;
            float psum = 0.f;
            #pragma unroll
            for (int rt = 0; rt < 4; rt++) {
                float p0 = __expf(acc_s[rt][0] - mnew);
                float p1 = __expf(acc_s[rt][1] - mnew);
                float p2 = __expf(acc_s[rt][2] - mnew);
                float p3 = __expf(acc_s[rt][3] - mnew);
                psum += (p0 + p1) + (p2 + p3);
                uint2 pk;
                pk.x = (uint32_t)f2b(p0) | ((uint32_t)f2b(p1) << 16);
                pk.y = (uint32_t)f2b(p2) | ((uint32_t)f2b(p3) << 16);
                *(uint2*)&Pl[w][qt * 16 + l16][rt * 16 + quad * 4] = pk;
            }
            psum += __shfl_xor(psum, 16);
            psum += __shfl_xor(psum, 32);
            l_s[qt] = l_s[qt] * alpha + psum;
            #pragma unroll
            for (int r = 0; r < 4; r++) {
                float ar = __shfl(alpha, (lane & 48) | (quad * 4 + r));
                #pragma unroll
                for (int dt = 0; dt < 4; dt++) acc_o[qt][dt][r] *= ar;
            }
            // ---- O += P * V (P via wave-private LDS; no barrier) ----
            #pragma unroll
            for (int kb = 0; kb < 2; kb++) {
                short8 pf = *(const short8*)&Pl[w][qt * 16 + l16][kb * 32 + quad * 8];
                #pragma unroll
                for (int dt = 0; dt < 4; dt++)
                    acc_o[qt][dt] = __builtin_amdgcn_mfma_f32_16x16x32_bf16(
                        pf, vf[kb][dt], acc_o[qt][dt], 0, 0, 0);
            }
        }
        // ---- rotate pipelined kf ----
        #pragma unroll
        for (int rt = 0; rt < 4; rt++)
            #pragma unroll
            for (int kd = 0; kd < 2; kd++)
                kfc[rt][kd] = kfn[rt][kd];
    }

    // ---- epilogue: normalize by l (per-q via in-quad shuffle), store bf16 --
    #pragma unroll
    for (int qt = 0; qt < 2; qt++) {
        #pragma unroll
        for (int r = 0; r < 4; r++) {
            float lr = __shfl(l_s[qt], (lane & 48) | (quad * 4 + r));
            float inv = 1.0f / lr;
            int qg = q0w + qt * 16 + quad * 4 + r;
            uint16_t* yp = y + (size_t)(b * T_ + qg) * 1024 + h * 64;
            #pragma unroll
            for (int dt = 0; dt < 4; dt++)
                yp[dt * 16 + l16] = f2b(acc_o[qt][dt][r] * inv);
        }
    }
}

extern "C" void kernel_launch(void* const* d_in, const int* in_sizes, int n_in,
                              void* d_out, int out_size, void* d_ws, size_t ws_size,
                              hipStream_t stream) {
    const float* x      = (const float*)d_in[0];  // [B,T,C] fp32
    const float* w_qkv  = (const float*)d_in[1];  // [C, 3HD] fp32
    const float* w_proj = (const float*)d_in[2];  // [HD, C] fp32
    const float* sink   = (const float*)d_in[3];  // [H] fp32
    float* out          = (float*)d_out;          // [B,T,C] fp32

    char* ws = (char*)d_ws;
    uint16_t* wt_qkv  = (uint16_t*)ws;                       // [3072,1024] 6.29 MB
    uint16_t* wt_proj = (uint16_t*)(ws + 6291456);           // [1024,1024] 2.10 MB
    uint16_t* x_c     = (uint16_t*)(ws + 8388608);           // 8.39 MB; reused as Kf
    uint16_t* qkv     = (uint16_t*)(ws + 16777216);          // [4096,3072] 25.17 MB
    uint16_t* yb      = (uint16_t*)(ws + 41943040);          // [4096,1024] 8.39 MB
    uint16_t* Vf      = (uint16_t*)(ws + 50331648);          // 8.39 MB (frag V)
    uint16_t* Kf      = x_c;                                 // x_c dead after GEMM1

    canon_x<<<4194304 / 1024, 256, 0, stream>>>(x, x_c, 4194304);
    transpose_conv<<<dim3(3072 / 32, 1024 / 32), dim3(32, 8), 0, stream>>>(
        w_qkv, wt_qkv, 1024, 3072);
    transpose_conv<<<dim3(1024 / 32, 1024 / 32), dim3(32, 8), 0, stream>>>(
        w_proj, wt_proj, 1024, 1024);

    gemm_bt<false><<<dim3(4096 / 128, 3072 / 128), 256, 0, stream>>>(
        x_c, wt_qkv, qkv, 4096, 3072, 1024);

    // repack K,V to fragment-linear (1024 blocks: bh*32+kt)
    repack_kv<<<dim3(32 * 32), 256, 0, stream>>>(qkv, Kf, Vf);

    // barrier-free attention: 512 blocks, 4 independent waves each
    attn_mfma<<<dim3(512), 256, 0, stream>>>(qkv, Kf, Vf, sink, yb);

    gemm_bt<true><<<dim3(4096 / 128, 1024 / 128), 256, 0, stream>>>(
        yb, wt_proj, out, 4096, 1024, 1024);
}